// Round 9
// baseline (236.611 us; speedup 1.0000x reference)
//
#include <hip/hip_runtime.h>
#include <math.h>

#define B_SZ 4
#define LQ_SZ 2048
#define C_SZ 256
#define NH_SZ 8
#define NL_SZ 4
#define NP_SZ 8
#define HD_SZ 32
#define LV_SZ 21760
#define NQ_SZ (B_SZ * LQ_SZ)   // 8192
#define MV_SZ (B_SZ * LV_SZ)   // 87040

typedef __attribute__((ext_vector_type(8))) short bf16x8;
typedef __attribute__((ext_vector_type(8))) unsigned short ushort8;
typedef __attribute__((ext_vector_type(4))) float f32x4;

__device__ __forceinline__ float bf2f(unsigned short u) {
  union { float f; unsigned v; } x;
  x.v = ((unsigned)u) << 16;
  return x.f;
}
__device__ __forceinline__ unsigned short f2bf(float f) {
  union { float f; unsigned v; } x;
  x.f = f;
  unsigned r = x.v + 0x7fffu + ((x.v >> 16) & 1u);
  return (unsigned short)(r >> 16);
}

// 8x f32 -> bf16x8 via v_cvt_pk_bf16_f32 (RNE, same as f2bf)
__device__ __forceinline__ bf16x8 cvt8(f32x4 a, f32x4 b) {
  union { unsigned u[4]; bf16x8 v; } r;
  asm("v_cvt_pk_bf16_f32 %0, %1, %2" : "=v"(r.u[0]) : "v"(a[0]), "v"(a[1]));
  asm("v_cvt_pk_bf16_f32 %0, %1, %2" : "=v"(r.u[1]) : "v"(a[2]), "v"(a[3]));
  asm("v_cvt_pk_bf16_f32 %0, %1, %2" : "=v"(r.u[2]) : "v"(b[0]), "v"(b[1]));
  asm("v_cvt_pk_bf16_f32 %0, %1, %2" : "=v"(r.u[3]) : "v"(b[2]), "v"(b[3]));
  return r.v;
}

// ---------------------------------------------------------------------------
// One-off weight preps (all tiny)
// ---------------------------------------------------------------------------
__global__ void convert_wt(const float* __restrict__ W,
                           unsigned short* __restrict__ Wt) {
  const int n = blockIdx.x, k = threadIdx.x;   // W is (256,256)
  Wt[n * 256 + k] = f2bf(W[k * 256 + n]);
}

// wcat[n][k], n<512: W_off, n<768: W_attn, n<896: Wa1, else 0
__global__ void build_wcat(const float* __restrict__ W_off,
                           const float* __restrict__ W_attn,
                           const float* __restrict__ Wa1,
                           unsigned short* __restrict__ wcat) {
  const int n = blockIdx.x, k = threadIdx.x;
  float v;
  if (n < 512) v = W_off[k * 512 + n];
  else if (n < 768) v = W_attn[k * 256 + (n - 512)];
  else if (n < 896) v = Wa1[k * 128 + (n - 768)];
  else v = 0.f;
  wcat[n * 256 + k] = f2bf(v);
}

__global__ void build_bcat(const float* __restrict__ b_off,
                           const float* __restrict__ b_attn,
                           const float* __restrict__ ba1,
                           float* __restrict__ bcat) {
  const int idx = blockIdx.x * 256 + threadIdx.x;
  float v;
  if (idx < 512) v = b_off[idx];
  else if (idx < 768) v = b_attn[idx - 512];
  else if (idx < 896) v = ba1[idx - 768];
  else v = 0.f;
  bcat[idx] = v;
}

// wa2t[n][k] = bf16(Wa2[k][n]), Wa2 is (128,512)
__global__ void build_wa2t(const float* __restrict__ Wa2,
                           unsigned short* __restrict__ wa2t) {
  const int n = blockIdx.x, k = threadIdx.x;
  wa2t[n * 128 + k] = f2bf(Wa2[k * 512 + n]);
}

// ---------------------------------------------------------------------------
// Wave-independent tall-skinny MFMA GEMM: C[M,n_total] = A[M,256]f32 @ Wt^T.
// Each WAVE owns 16 rows x 256 cols. Zero LDS, zero barriers. The wave's
// whole A-slice is loaded up front as 16 independent 1-KB wave-loads
// (16 B/lane) -> cvt_pk -> 32 VGPRs of bf16 fragments; the K-loop touches
// only the 128-KB L1/L2-hot Wt (8+8 fragment loads per k-step) + 16 MFMA.
// Block = 4 independent waves. grid = (M/64, n_total/256).
// ---------------------------------------------------------------------------
template <int OUT_BF16>
__global__ __launch_bounds__(256, 3) void gemm_tall(
    const float* __restrict__ A, const unsigned short* __restrict__ Wt,
    const float* __restrict__ bias, void* __restrict__ Cout, int n_total) {
  const int tid = threadIdx.x;
  const int lane = tid & 63;
  const int w = tid >> 6;
  const long bm = ((long)blockIdx.x * 4 + w) * 16;
  const int bn0 = blockIdx.y * 256;
  const int rowc = lane & 15, rowg = lane >> 4;

  // ---- A phase: 16 independent loads, then convert ----
  bf16x8 afrag[8];
  {
    const float* ap = A + (bm + rowc) * 256 + rowg * 8;
    f32x4 st0[8], st1[8];
#pragma unroll
    for (int ks = 0; ks < 8; ++ks) {
      st0[ks] = *(const f32x4*)(ap + ks * 32);
      st1[ks] = *(const f32x4*)(ap + ks * 32 + 4);
    }
#pragma unroll
    for (int ks = 0; ks < 8; ++ks) afrag[ks] = cvt8(st0[ks], st1[ks]);
  }

  f32x4 acc[16];
#pragma unroll
  for (int n = 0; n < 16; ++n) acc[n] = (f32x4){0.f, 0.f, 0.f, 0.f};

  // ---- K loop: B fragments from L1/L2-hot weights, two windows of 8 ----
  const unsigned short* wp = Wt + (long)(bn0 + rowc) * 256 + rowg * 8;
#pragma unroll
  for (int ks = 0; ks < 8; ++ks) {
    bf16x8 bf[8];
#pragma unroll
    for (int n = 0; n < 8; ++n)
      bf[n] = *(const bf16x8*)(wp + (long)n * 16 * 256 + ks * 32);
#pragma unroll
    for (int n = 0; n < 8; ++n)
      acc[n] = __builtin_amdgcn_mfma_f32_16x16x32_bf16(afrag[ks], bf[n],
                                                       acc[n], 0, 0, 0);
#pragma unroll
    for (int n = 0; n < 8; ++n)
      bf[n] = *(const bf16x8*)(wp + (long)(n + 8) * 16 * 256 + ks * 32);
#pragma unroll
    for (int n = 0; n < 8; ++n)
      acc[n + 8] = __builtin_amdgcn_mfma_f32_16x16x32_bf16(afrag[ks], bf[n],
                                                           acc[n + 8], 0, 0, 0);
  }

  // ---- epilogue: C[bm + rowg*4 + j][bn0 + n*16 + rowc] ----
#pragma unroll
  for (int n = 0; n < 16; ++n) {
    const int col = bn0 + n * 16 + rowc;
    const float bb = bias[col];
#pragma unroll
    for (int j = 0; j < 4; ++j) {
      const long row = bm + rowg * 4 + j;
      const float val = acc[n][j] + bb;
      if (OUT_BF16)
        ((unsigned short*)Cout)[row * n_total + col] = f2bf(val);
      else
        ((float*)Cout)[row * n_total + col] = val;
    }
  }
}

// ---------------------------------------------------------------------------
// Reg-staged MFMA GEMM (kept for bf16-A off2): C = A[M,128]bf16 @ Wt^T + b
// ---------------------------------------------------------------------------
#define AS_STRIDE 40  // ushorts per LDS row (80 B -> only free 2-way aliasing)

template <int OUT_BF16, int A_BF16, int K_DIM>
__global__ __launch_bounds__(512, 1) void gemm_mfma(
    const void* __restrict__ Ain, const unsigned short* __restrict__ Wt,
    const float* __restrict__ bias, void* __restrict__ Cout, int n_total) {
  constexpr int KSTEPS = K_DIM / 32;
  __shared__ unsigned short As[2][128 * AS_STRIDE];
  const int tid = threadIdx.x;
  const long bm = (long)blockIdx.x * 128;
  const int bn0 = blockIdx.y * 256;
  const int lane = tid & 63;
  const int wid = tid >> 6;
  const int wr = wid >> 2;
  const int wc = wid & 3;
  const int rowg = (lane >> 4);
  const int rowc = lane & 15;

  const int srow = tid >> 2;
  const int skc = (tid & 3) * 8;

  f32x4 acc[4][4];
#pragma unroll
  for (int m = 0; m < 4; ++m)
#pragma unroll
    for (int n = 0; n < 4; ++n) acc[m][n] = (f32x4){0.f, 0.f, 0.f, 0.f};

  const unsigned short* srcb =
      (const unsigned short*)Ain + (bm + srow) * (long)K_DIM + skc;

  {
    ushort8 u = *(const ushort8*)srcb;
    *(ushort8*)&As[0][srow * AS_STRIDE + skc] = u;
  }
  __syncthreads();

  int cur = 0;
#pragma unroll
  for (int ks = 0; ks < KSTEPS; ++ks) {
    ushort8 pre;
    if (ks < KSTEPS - 1) pre = *(const ushort8*)(srcb + (ks + 1) * 32);
    bf16x8 bfrag[4];
#pragma unroll
    for (int n = 0; n < 4; ++n) {
      const unsigned short* wp =
          Wt + (long)(bn0 + wc * 64 + n * 16 + rowc) * K_DIM + ks * 32 +
          rowg * 8;
      bfrag[n] = *(const bf16x8*)wp;
    }
    bf16x8 afrag[4];
#pragma unroll
    for (int m = 0; m < 4; ++m) {
      const int r = wr * 64 + m * 16 + rowc;
      afrag[m] = *(const bf16x8*)&As[cur][r * AS_STRIDE + rowg * 8];
    }
#pragma unroll
    for (int m = 0; m < 4; ++m)
#pragma unroll
      for (int n = 0; n < 4; ++n)
        acc[m][n] = __builtin_amdgcn_mfma_f32_16x16x32_bf16(
            afrag[m], bfrag[n], acc[m][n], 0, 0, 0);

    if (ks < KSTEPS - 1) {
      *(ushort8*)&As[cur ^ 1][srow * AS_STRIDE + skc] = pre;
    }
    __syncthreads();
    cur ^= 1;
  }

#pragma unroll
  for (int m = 0; m < 4; ++m) {
#pragma unroll
    for (int n = 0; n < 4; ++n) {
      const int col = bn0 + wc * 64 + n * 16 + rowc;
      const float bb = bias[col];
#pragma unroll
      for (int j = 0; j < 4; ++j) {
        const long row = bm + wr * 64 + m * 16 + rowg * 4 + j;
        const float val = acc[m][n][j] + bb;
        if (OUT_BF16)
          ((unsigned short*)Cout)[row * n_total + col] = f2bf(val);
        else
          ((float*)Cout)[row * n_total + col] = val;
      }
    }
  }
}

// ---------------------------------------------------------------------------
// hidb = bf16(relu(proj[:, 768:896]))
// ---------------------------------------------------------------------------
__global__ __launch_bounds__(256) void relu_hid(const float* __restrict__ proj,
                                                unsigned short* __restrict__ hidb) {
  const int idx = blockIdx.x * 256 + threadIdx.x;  // < 8192*128
  const int q = idx >> 7, j = idx & 127;
  hidb[idx] = f2bf(fmaxf(proj[(long)q * 1024 + 768 + j], 0.f));
}

// ---------------------------------------------------------------------------
// finalize: grid coords + softmax attention weights.
// ---------------------------------------------------------------------------
__global__ __launch_bounds__(256) void finalize_qproj(
    const float* __restrict__ proj, const float* __restrict__ off2,
    const float* __restrict__ refpts, float* __restrict__ grid_out,
    float* __restrict__ aw_out) {
  const int tid = threadIdx.x;
  const long q0 = (long)blockIdx.x * 16;
#pragma unroll 4
  for (int q = 0; q < 16; ++q) {
    const long qi = q0 + q;
    const float* pr = proj + qi * 1024;
    float logit = pr[512 + tid];
    float m = logit;
#pragma unroll
    for (int mask = 16; mask > 0; mask >>= 1)
      m = fmaxf(m, __shfl_xor(m, mask));
    float e = __expf(logit - m);
    float s = e;
#pragma unroll
    for (int mask = 16; mask > 0; mask >>= 1) s += __shfl_xor(s, mask);
    aw_out[qi * 256 + tid] = e / s;
#pragma unroll
    for (int half = 0; half < 2; ++half) {
      const int o = tid + half * 256;
      const float offv = pr[o] + 0.1f * off2[qi * 512 + o];
      const int l = (o >> 4) & 3;
      const int c = o & 1;
      const float rnorm = 1.f / (float)(128 >> l);
      const float ref = refpts[qi * 8 + l * 2 + c];
      grid_out[qi * 512 + o] = (ref + offv * rnorm) * 2.f - 1.f;
    }
  }
}

// ---------------------------------------------------------------------------
// Bilinear sampling + attention-weighted accumulation. v is bf16.
// ---------------------------------------------------------------------------
__global__ __launch_bounds__(256) void sample_kernel(
    const unsigned short* __restrict__ v, const float* __restrict__ grid,
    const float* __restrict__ aw, float* __restrict__ acc_out) {
  __shared__ int4 sidx[512];
  __shared__ float4 sw[512];
  const int tid = threadIdx.x;
  const long q0 = (long)blockIdx.x * 2;
  const int b = (int)(q0 >> 11);
  constexpr int starts[4] = {0, 16384, 20480, 21504};

#pragma unroll
  for (int ss = 0; ss < 2; ++ss) {
    const int s = tid + ss * 256;
    const int qq = s >> 8, j = s & 255;       // j = h*32 + l*8 + p
    const int l = (j >> 3) & 3;
    const int HW = 128 >> l;
    const float fHW = (float)HW;
    const float2 g = *(const float2*)(grid + (q0 + qq) * 512 + 2 * j);
    const float w = aw[(q0 + qq) * 256 + j];
    const float x = ((g.x + 1.f) * fHW - 1.f) * 0.5f;
    const float y = ((g.y + 1.f) * fHW - 1.f) * 0.5f;
    const float x0f = floorf(x), y0f = floorf(y);
    const float lx = x - x0f, ly = y - y0f;
    const int ix0 = (int)x0f, iy0 = (int)y0f;
    const int ix1 = ix0 + 1, iy1 = iy0 + 1;
    const float vx0 = (ix0 >= 0 && ix0 < HW) ? 1.f : 0.f;
    const float vx1 = (ix1 >= 0 && ix1 < HW) ? 1.f : 0.f;
    const float vy0 = (iy0 >= 0 && iy0 < HW) ? 1.f : 0.f;
    const float vy1 = (iy1 >= 0 && iy1 < HW) ? 1.f : 0.f;
    const int cx0 = min(max(ix0, 0), HW - 1);
    const int cx1 = min(max(ix1, 0), HW - 1);
    const int cy0 = min(max(iy0, 0), HW - 1);
    const int cy1 = min(max(iy1, 0), HW - 1);
    const int base = starts[l];
    int4 o;  // byte offsets into v (256 ch * 2 B per location)
    o.x = (base + cy0 * HW + cx0) * 512;
    o.y = (base + cy0 * HW + cx1) * 512;
    o.z = (base + cy1 * HW + cx0) * 512;
    o.w = (base + cy1 * HW + cx1) * 512;
    sidx[s] = o;
    float4 wv;
    wv.x = (1.f - lx) * (1.f - ly) * vx0 * vy0 * w;
    wv.y = lx * (1.f - ly) * vx1 * vy0 * w;
    wv.z = (1.f - lx) * ly * vx0 * vy1 * w;
    wv.w = lx * ly * vx1 * vy1 * w;
    sw[s] = wv;
  }
  __syncthreads();

  const int qq = tid >> 7, h = (tid >> 4) & 7, dp = tid & 15;
  const char* vb =
      (const char*)v + ((long)b * LV_SZ * 256 + h * 32 + dp * 2) * 2;
  const int sbase = qq * 256 + h * 32;
  float acc0 = 0.f, acc1 = 0.f;
#pragma unroll 8
  for (int j = 0; j < 32; ++j) {
    const int4 o = sidx[sbase + j];
    const float4 w = sw[sbase + j];
    const ushort2 u0 = *(const ushort2*)(vb + o.x);
    const ushort2 u1 = *(const ushort2*)(vb + o.y);
    const ushort2 u2 = *(const ushort2*)(vb + o.z);
    const ushort2 u3 = *(const ushort2*)(vb + o.w);
    acc0 = fmaf(bf2f(u0.x), w.x, acc0);
    acc1 = fmaf(bf2f(u0.y), w.x, acc1);
    acc0 = fmaf(bf2f(u1.x), w.y, acc0);
    acc1 = fmaf(bf2f(u1.y), w.y, acc1);
    acc0 = fmaf(bf2f(u2.x), w.z, acc0);
    acc1 = fmaf(bf2f(u2.y), w.z, acc1);
    acc0 = fmaf(bf2f(u3.x), w.w, acc0);
    acc1 = fmaf(bf2f(u3.y), w.w, acc1);
  }
  float2 res = {acc0, acc1};
  *(float2*)(acc_out + (q0 + qq) * 256 + h * 32 + dp * 2) = res;
}

// ---------------------------------------------------------------------------
extern "C" void kernel_launch(void* const* d_in, const int* in_sizes, int n_in,
                              void* d_out, int out_size, void* d_ws,
                              size_t ws_size, hipStream_t stream) {
  const float* query  = (const float*)d_in[0];
  const float* refpts = (const float*)d_in[1];
  const float* value  = (const float*)d_in[2];
  const float* W_off  = (const float*)d_in[5];
  const float* b_off  = (const float*)d_in[6];
  const float* W_attn = (const float*)d_in[7];
  const float* b_attn = (const float*)d_in[8];
  const float* Wa1    = (const float*)d_in[9];
  const float* ba1    = (const float*)d_in[10];
  const float* Wa2    = (const float*)d_in[11];
  const float* ba2    = (const float*)d_in[12];
  const float* Wv     = (const float*)d_in[13];
  const float* bv     = (const float*)d_in[14];
  const float* Wo     = (const float*)d_in[15];
  const float* bo     = (const float*)d_in[16];
  float* out = (float*)d_out;

  char* ws = (char*)d_ws;
  // layout (total 122,556,416 B):
  unsigned short* v_ws = (unsigned short*)ws;                   // 44,564,480
  float* proj_ws = (float*)(ws + 44564480);                     // 33,554,432
  float* acc_ws  = (float*)(ws + 44564480);        // aliases proj (dead then)
  float* off2_ws = (float*)(ws + 78118912);                     // 16,777,216
  unsigned short* wcat_ws = (unsigned short*)(ws + 78118912);   // aliases off2
  unsigned short* hidb_ws = (unsigned short*)(ws + 94896128);   //  2,097,152
  float* grid_ws = (float*)(ws + 96993280);                     // 16,777,216
  float* aw_ws   = (float*)(ws + 113770496);                    //  8,388,608
  unsigned short* wtv_ws  = (unsigned short*)(ws + 122159104);  //    131,072
  unsigned short* wto_ws  = (unsigned short*)(ws + 122290176);  //    131,072
  unsigned short* wa2t_ws = (unsigned short*)(ws + 122421248);  //    131,072
  float* bcat_ws = (float*)(ws + 122552320);                    //      4,096

  // 0) weight preps
  convert_wt<<<256, 256, 0, stream>>>(Wv, wtv_ws);
  convert_wt<<<256, 256, 0, stream>>>(Wo, wto_ws);
  build_wcat<<<1024, 256, 0, stream>>>(W_off, W_attn, Wa1, wcat_ws);
  build_bcat<<<4, 256, 0, stream>>>(b_off, b_attn, ba1, bcat_ws);
  build_wa2t<<<512, 128, 0, stream>>>(Wa2, wa2t_ws);
  // 1) v = value @ Wv + bv  (bf16 out)
  gemm_tall<1><<<dim3(MV_SZ / 64, 1), 256, 0, stream>>>(
      value, wtv_ws, bv, v_ws, 256);
  // 2) proj = query @ [W_off|W_attn|Wa1|0] + bcat
  gemm_tall<0><<<dim3(NQ_SZ / 64, 4), 256, 0, stream>>>(
      query, wcat_ws, bcat_ws, proj_ws, 1024);
  // 3) hidb = bf16(relu(proj[:,768:896]))
  relu_hid<<<NQ_SZ * 128 / 256, 256, 0, stream>>>(proj_ws, hidb_ws);
  // 4) off2 = hidb @ Wa2 + ba2
  gemm_mfma<0, 1, 128><<<dim3(NQ_SZ / 128, 2), 512, 0, stream>>>(
      hidb_ws, wa2t_ws, ba2, off2_ws, 512);
  // 5) grids + attention weights
  finalize_qproj<<<NQ_SZ / 16, 256, 0, stream>>>(proj_ws, off2_ws, refpts,
                                                 grid_ws, aw_ws);
  // 6) bilinear sampling + weighted accumulation
  sample_kernel<<<NQ_SZ / 2, 256, 0, stream>>>(v_ws, grid_ws, aw_ws, acc_ws);
  // 7) out = acc @ Wo + bo
  gemm_tall<0><<<dim3(NQ_SZ / 64, 1), 256, 0, stream>>>(
      acc_ws, wto_ws, bo, out, 256);
}

// Round 10
// 142.323 us; speedup vs baseline: 1.6625x; 1.6625x over previous
//
#include <hip/hip_runtime.h>
#include <math.h>

#define B_SZ 4
#define LQ_SZ 2048
#define C_SZ 256
#define NH_SZ 8
#define NL_SZ 4
#define NP_SZ 8
#define HD_SZ 32
#define LV_SZ 21760
#define NQ_SZ (B_SZ * LQ_SZ)   // 8192
#define MV_SZ (B_SZ * LV_SZ)   // 87040

typedef __attribute__((ext_vector_type(8))) short bf16x8;
typedef __attribute__((ext_vector_type(8))) unsigned short ushort8;
typedef __attribute__((ext_vector_type(4))) float f32x4;

__device__ __forceinline__ float bf2f(unsigned short u) {
  union { float f; unsigned v; } x;
  x.v = ((unsigned)u) << 16;
  return x.f;
}
__device__ __forceinline__ unsigned short f2bf(float f) {
  union { float f; unsigned v; } x;
  x.f = f;
  unsigned r = x.v + 0x7fffu + ((x.v >> 16) & 1u);
  return (unsigned short)(r >> 16);
}

// ---------------------------------------------------------------------------
// One-shot weight prep, all ranges in a single dispatch (grid 1796 x 256).
//   [0,256)    wtv[n][k]  = bf16(Wv[k][n])
//   [256,512)  wto[n][k]  = bf16(Wo[k][n])
//   [512,1536) wcat[n][k] : n<512 W_off | n<768 W_attn | n<896 Wa1 | 0
//   [1536,1792) wa2t[n][k] = bf16(Wa2[k][n])   (512x128)
//   [1792,1796) bcat[idx] : b_off | b_attn | ba1 | 0   (1024)
// ---------------------------------------------------------------------------
__global__ void prep_weights(
    const float* __restrict__ Wv, const float* __restrict__ Wo,
    const float* __restrict__ W_off, const float* __restrict__ W_attn,
    const float* __restrict__ Wa1, const float* __restrict__ Wa2,
    const float* __restrict__ b_off, const float* __restrict__ b_attn,
    const float* __restrict__ ba1,
    unsigned short* __restrict__ wtv, unsigned short* __restrict__ wto,
    unsigned short* __restrict__ wcat, unsigned short* __restrict__ wa2t,
    float* __restrict__ bcat) {
  const int bid = blockIdx.x, t = threadIdx.x;
  if (bid < 256) {
    wtv[bid * 256 + t] = f2bf(Wv[t * 256 + bid]);
  } else if (bid < 512) {
    const int n = bid - 256;
    wto[n * 256 + t] = f2bf(Wo[t * 256 + n]);
  } else if (bid < 1536) {
    const int n = bid - 512;
    float v;
    if (n < 512) v = W_off[t * 512 + n];
    else if (n < 768) v = W_attn[t * 256 + (n - 512)];
    else if (n < 896) v = Wa1[t * 128 + (n - 768)];
    else v = 0.f;
    wcat[n * 256 + t] = f2bf(v);
  } else if (bid < 1792) {
    const int idx = (bid - 1536) * 256 + t;     // < 65536
    const int n = idx >> 7, k = idx & 127;
    wa2t[n * 128 + k] = f2bf(Wa2[k * 512 + n]);
  } else {
    const int idx = (bid - 1792) * 256 + t;     // < 1024
    float v;
    if (idx < 512) v = b_off[idx];
    else if (idx < 768) v = b_attn[idx - 512];
    else if (idx < 896) v = ba1[idx - 768];
    else v = 0.f;
    bcat[idx] = v;
  }
}

#define AS_STRIDE 40  // ushorts per LDS row (80 B -> only free 2-way aliasing)

// ---------------------------------------------------------------------------
// FUSED value-GEMM + proj-GEMM, one dispatch (grid 1024 x 512 threads).
// Interleave: (bid&3)==3 -> proj tile, else value tile, so memory-stalled
// value blocks and compute-heavy proj blocks co-reside per CU.
//   value: v[87040,256]bf16 = value @ wtv^T + bv        (680 tiles of 128)
//   proj : proj[8192,768]f32 / hidb[8192,128]bf16(relu) (64x4 tiles)
// Body = round-5 reg-staged double-buffered MFMA (best measured).
// ---------------------------------------------------------------------------
__global__ __launch_bounds__(512, 1) void gemm_fused(
    const float* __restrict__ value, const unsigned short* __restrict__ wtv,
    const float* __restrict__ bv, unsigned short* __restrict__ v_out,
    const float* __restrict__ query, const unsigned short* __restrict__ wcat,
    const float* __restrict__ bcat, float* __restrict__ proj_out,
    unsigned short* __restrict__ hidb) {
  __shared__ unsigned short As[2][128 * AS_STRIDE];
  const int bid = blockIdx.x;
  const float* A;
  const unsigned short* Wt;
  const float* bias;
  long bm;
  int bn0, mode;
  if ((bid & 3) == 3) {
    const int p = bid >> 2;          // 0..255
    bm = (long)(p >> 2) * 128;       // 64 row tiles
    bn0 = (p & 3) * 256;
    A = query; Wt = wcat; bias = bcat; mode = 1;
  } else {
    const int vt = (bid >> 2) * 3 + (bid & 3);  // 0..767
    if (vt >= 680) return;
    bm = (long)vt * 128;
    bn0 = 0;
    A = value; Wt = wtv; bias = bv; mode = 0;
  }

  const int tid = threadIdx.x;
  const int lane = tid & 63;
  const int wid = tid >> 6;
  const int wr = wid >> 2, wc = wid & 3;
  const int rowg = lane >> 4, rowc = lane & 15;
  const int srow = tid >> 2;
  const int skc = (tid & 3) * 8;

  f32x4 acc[4][4];
#pragma unroll
  for (int m = 0; m < 4; ++m)
#pragma unroll
    for (int n = 0; n < 4; ++n) acc[m][n] = (f32x4){0.f, 0.f, 0.f, 0.f};

  const float* srcf = A + (bm + srow) * 256 + skc;

  {
    float4 f0 = *(const float4*)(srcf + 0);
    float4 f1 = *(const float4*)(srcf + 4);
    ushort8 u;
    u[0] = f2bf(f0.x); u[1] = f2bf(f0.y); u[2] = f2bf(f0.z); u[3] = f2bf(f0.w);
    u[4] = f2bf(f1.x); u[5] = f2bf(f1.y); u[6] = f2bf(f1.z); u[7] = f2bf(f1.w);
    *(ushort8*)&As[0][srow * AS_STRIDE + skc] = u;
  }
  __syncthreads();

  int cur = 0;
#pragma unroll
  for (int ks = 0; ks < 8; ++ks) {
    ushort8 pre;
    if (ks < 7) {
      float4 f0 = *(const float4*)(srcf + (ks + 1) * 32 + 0);
      float4 f1 = *(const float4*)(srcf + (ks + 1) * 32 + 4);
      pre[0] = f2bf(f0.x); pre[1] = f2bf(f0.y);
      pre[2] = f2bf(f0.z); pre[3] = f2bf(f0.w);
      pre[4] = f2bf(f1.x); pre[5] = f2bf(f1.y);
      pre[6] = f2bf(f1.z); pre[7] = f2bf(f1.w);
    }
    bf16x8 bfrag[4];
#pragma unroll
    for (int n = 0; n < 4; ++n) {
      bfrag[n] = *(const bf16x8*)(
          Wt + (long)(bn0 + wc * 64 + n * 16 + rowc) * 256 + ks * 32 +
          rowg * 8);
    }
    bf16x8 afrag[4];
#pragma unroll
    for (int m = 0; m < 4; ++m) {
      const int r = wr * 64 + m * 16 + rowc;
      afrag[m] = *(const bf16x8*)&As[cur][r * AS_STRIDE + rowg * 8];
    }
#pragma unroll
    for (int m = 0; m < 4; ++m)
#pragma unroll
      for (int n = 0; n < 4; ++n)
        acc[m][n] = __builtin_amdgcn_mfma_f32_16x16x32_bf16(
            afrag[m], bfrag[n], acc[m][n], 0, 0, 0);

    if (ks < 7) {
      *(ushort8*)&As[cur ^ 1][srow * AS_STRIDE + skc] = pre;
    }
    __syncthreads();
    cur ^= 1;
  }

#pragma unroll
  for (int m = 0; m < 4; ++m) {
#pragma unroll
    for (int n = 0; n < 4; ++n) {
      const int col = bn0 + wc * 64 + n * 16 + rowc;
      const float bb = bias[col];
#pragma unroll
      for (int j = 0; j < 4; ++j) {
        const long row = bm + wr * 64 + m * 16 + rowg * 4 + j;
        const float val = acc[m][n][j] + bb;
        if (mode == 0) {
          v_out[row * 256 + col] = f2bf(val);
        } else if (col < 768) {
          proj_out[row * 1024 + col] = val;
        } else if (col < 896) {
          hidb[row * 128 + (col - 768)] = f2bf(fmaxf(val, 0.f));
        }
      }
    }
  }
}

// ---------------------------------------------------------------------------
// Reg-staged MFMA GEMM (round-5 template): C = A[M,K_DIM] @ Wt^T + bias
// ---------------------------------------------------------------------------
template <int OUT_BF16, int A_BF16, int K_DIM>
__global__ __launch_bounds__(512, 1) void gemm_mfma(
    const void* __restrict__ Ain, const unsigned short* __restrict__ Wt,
    const float* __restrict__ bias, void* __restrict__ Cout, int n_total) {
  constexpr int KSTEPS = K_DIM / 32;
  __shared__ unsigned short As[2][128 * AS_STRIDE];
  const int tid = threadIdx.x;
  const long bm = (long)blockIdx.x * 128;
  const int bn0 = blockIdx.y * 256;
  const int lane = tid & 63;
  const int wid = tid >> 6;
  const int wr = wid >> 2;
  const int wc = wid & 3;
  const int rowg = (lane >> 4);
  const int rowc = lane & 15;
  const int srow = tid >> 2;
  const int skc = (tid & 3) * 8;

  f32x4 acc[4][4];
#pragma unroll
  for (int m = 0; m < 4; ++m)
#pragma unroll
    for (int n = 0; n < 4; ++n) acc[m][n] = (f32x4){0.f, 0.f, 0.f, 0.f};

  const float* srcf = (const float*)Ain + (bm + srow) * (long)K_DIM + skc;
  const unsigned short* srcb =
      (const unsigned short*)Ain + (bm + srow) * (long)K_DIM + skc;

  {
    ushort8 u;
    if constexpr (A_BF16) {
      u = *(const ushort8*)srcb;
    } else {
      float4 f0 = *(const float4*)(srcf + 0);
      float4 f1 = *(const float4*)(srcf + 4);
      u[0] = f2bf(f0.x); u[1] = f2bf(f0.y); u[2] = f2bf(f0.z); u[3] = f2bf(f0.w);
      u[4] = f2bf(f1.x); u[5] = f2bf(f1.y); u[6] = f2bf(f1.z); u[7] = f2bf(f1.w);
    }
    *(ushort8*)&As[0][srow * AS_STRIDE + skc] = u;
  }
  __syncthreads();

  int cur = 0;
#pragma unroll
  for (int ks = 0; ks < KSTEPS; ++ks) {
    ushort8 pre;
    if (ks < KSTEPS - 1) {
      if constexpr (A_BF16) {
        pre = *(const ushort8*)(srcb + (ks + 1) * 32);
      } else {
        float4 f0 = *(const float4*)(srcf + (ks + 1) * 32 + 0);
        float4 f1 = *(const float4*)(srcf + (ks + 1) * 32 + 4);
        pre[0] = f2bf(f0.x); pre[1] = f2bf(f0.y);
        pre[2] = f2bf(f0.z); pre[3] = f2bf(f0.w);
        pre[4] = f2bf(f1.x); pre[5] = f2bf(f1.y);
        pre[6] = f2bf(f1.z); pre[7] = f2bf(f1.w);
      }
    }
    bf16x8 bfrag[4];
#pragma unroll
    for (int n = 0; n < 4; ++n) {
      const unsigned short* wp =
          Wt + (long)(bn0 + wc * 64 + n * 16 + rowc) * K_DIM + ks * 32 +
          rowg * 8;
      bfrag[n] = *(const bf16x8*)wp;
    }
    bf16x8 afrag[4];
#pragma unroll
    for (int m = 0; m < 4; ++m) {
      const int r = wr * 64 + m * 16 + rowc;
      afrag[m] = *(const bf16x8*)&As[cur][r * AS_STRIDE + rowg * 8];
    }
#pragma unroll
    for (int m = 0; m < 4; ++m)
#pragma unroll
      for (int n = 0; n < 4; ++n)
        acc[m][n] = __builtin_amdgcn_mfma_f32_16x16x32_bf16(
            afrag[m], bfrag[n], acc[m][n], 0, 0, 0);

    if (ks < KSTEPS - 1) {
      *(ushort8*)&As[cur ^ 1][srow * AS_STRIDE + skc] = pre;
    }
    __syncthreads();
    cur ^= 1;
  }

#pragma unroll
  for (int m = 0; m < 4; ++m) {
#pragma unroll
    for (int n = 0; n < 4; ++n) {
      const int col = bn0 + wc * 64 + n * 16 + rowc;
      const float bb = bias[col];
#pragma unroll
      for (int j = 0; j < 4; ++j) {
        const long row = bm + wr * 64 + m * 16 + rowg * 4 + j;
        const float val = acc[m][n][j] + bb;
        if (OUT_BF16)
          ((unsigned short*)Cout)[row * n_total + col] = f2bf(val);
        else
          ((float*)Cout)[row * n_total + col] = val;
      }
    }
  }
}

// ---------------------------------------------------------------------------
// Sampling with FUSED finalize: phase 1 computes softmax weights + grid
// coords directly from proj/off2/refpts, then corner offsets + fused
// weights into LDS; phase 2 gathers v. Block = 2 queries, 256 threads.
// ---------------------------------------------------------------------------
__global__ __launch_bounds__(256) void sample_kernel(
    const unsigned short* __restrict__ v, const float* __restrict__ proj,
    const float* __restrict__ off2, const float* __restrict__ refpts,
    float* __restrict__ acc_out) {
  __shared__ int4 sidx[512];
  __shared__ float4 sw[512];
  const int tid = threadIdx.x;
  const long q0 = (long)blockIdx.x * 2;
  const int b = (int)(q0 >> 11);
  constexpr int starts[4] = {0, 16384, 20480, 21504};

  // ---- phase 1: softmax + grid + corner offsets/weights ----
#pragma unroll
  for (int ss = 0; ss < 2; ++ss) {
    const int s = tid + ss * 256;
    const int qq = s >> 8, j = s & 255;       // j = h*32 + l*8 + p
    const long qi = q0 + qq;
    const int l = (j >> 3) & 3;
    const int HW = 128 >> l;
    const float fHW = (float)HW;

    // softmax over the 32-sample head group (j groups align to 32 lanes)
    const float logit = proj[qi * 1024 + 512 + j];
    float mx = logit;
#pragma unroll
    for (int mask = 16; mask > 0; mask >>= 1)
      mx = fmaxf(mx, __shfl_xor(mx, mask));
    const float e = __expf(logit - mx);
    float sum = e;
#pragma unroll
    for (int mask = 16; mask > 0; mask >>= 1) sum += __shfl_xor(sum, mask);
    const float w = e / sum;

    // sampling location
    const float2 po = *(const float2*)(proj + qi * 1024 + 2 * j);
    const float2 o2 = *(const float2*)(off2 + qi * 512 + 2 * j);
    const float2 rp = *(const float2*)(refpts + qi * 8 + l * 2);
    const float rnorm = 1.f / fHW;
    const float gx = (rp.x + (po.x + 0.1f * o2.x) * rnorm) * 2.f - 1.f;
    const float gy = (rp.y + (po.y + 0.1f * o2.y) * rnorm) * 2.f - 1.f;

    const float x = ((gx + 1.f) * fHW - 1.f) * 0.5f;
    const float y = ((gy + 1.f) * fHW - 1.f) * 0.5f;
    const float x0f = floorf(x), y0f = floorf(y);
    const float lx = x - x0f, ly = y - y0f;
    const int ix0 = (int)x0f, iy0 = (int)y0f;
    const int ix1 = ix0 + 1, iy1 = iy0 + 1;
    const float vx0 = (ix0 >= 0 && ix0 < HW) ? 1.f : 0.f;
    const float vx1 = (ix1 >= 0 && ix1 < HW) ? 1.f : 0.f;
    const float vy0 = (iy0 >= 0 && iy0 < HW) ? 1.f : 0.f;
    const float vy1 = (iy1 >= 0 && iy1 < HW) ? 1.f : 0.f;
    const int cx0 = min(max(ix0, 0), HW - 1);
    const int cx1 = min(max(ix1, 0), HW - 1);
    const int cy0 = min(max(iy0, 0), HW - 1);
    const int cy1 = min(max(iy1, 0), HW - 1);
    const int base = starts[l];
    int4 o;  // byte offsets into v (256 ch * 2 B per location)
    o.x = (base + cy0 * HW + cx0) * 512;
    o.y = (base + cy0 * HW + cx1) * 512;
    o.z = (base + cy1 * HW + cx0) * 512;
    o.w = (base + cy1 * HW + cx1) * 512;
    sidx[s] = o;
    float4 wv;
    wv.x = (1.f - lx) * (1.f - ly) * vx0 * vy0 * w;
    wv.y = lx * (1.f - ly) * vx1 * vy0 * w;
    wv.z = (1.f - lx) * ly * vx0 * vy1 * w;
    wv.w = lx * ly * vx1 * vy1 * w;
    sw[s] = wv;
  }
  __syncthreads();

  // ---- phase 2: gather + weighted accumulate, 2 channels/thread ----
  const int qq = tid >> 7, h = (tid >> 4) & 7, dp = tid & 15;
  const char* vb =
      (const char*)v + ((long)b * LV_SZ * 256 + h * 32 + dp * 2) * 2;
  const int sbase = qq * 256 + h * 32;
  float acc0 = 0.f, acc1 = 0.f;
#pragma unroll 8
  for (int j = 0; j < 32; ++j) {
    const int4 o = sidx[sbase + j];
    const float4 w = sw[sbase + j];
    const ushort2 u0 = *(const ushort2*)(vb + o.x);
    const ushort2 u1 = *(const ushort2*)(vb + o.y);
    const ushort2 u2 = *(const ushort2*)(vb + o.z);
    const ushort2 u3 = *(const ushort2*)(vb + o.w);
    acc0 = fmaf(bf2f(u0.x), w.x, acc0);
    acc1 = fmaf(bf2f(u0.y), w.x, acc1);
    acc0 = fmaf(bf2f(u1.x), w.y, acc0);
    acc1 = fmaf(bf2f(u1.y), w.y, acc1);
    acc0 = fmaf(bf2f(u2.x), w.z, acc0);
    acc1 = fmaf(bf2f(u2.y), w.z, acc1);
    acc0 = fmaf(bf2f(u3.x), w.w, acc0);
    acc1 = fmaf(bf2f(u3.y), w.w, acc1);
  }
  float2 res = {acc0, acc1};
  *(float2*)(acc_out + (q0 + qq) * 256 + h * 32 + dp * 2) = res;
}

// ---------------------------------------------------------------------------
extern "C" void kernel_launch(void* const* d_in, const int* in_sizes, int n_in,
                              void* d_out, int out_size, void* d_ws,
                              size_t ws_size, hipStream_t stream) {
  const float* query  = (const float*)d_in[0];
  const float* refpts = (const float*)d_in[1];
  const float* value  = (const float*)d_in[2];
  const float* W_off  = (const float*)d_in[5];
  const float* b_off  = (const float*)d_in[6];
  const float* W_attn = (const float*)d_in[7];
  const float* b_attn = (const float*)d_in[8];
  const float* Wa1    = (const float*)d_in[9];
  const float* ba1    = (const float*)d_in[10];
  const float* Wa2    = (const float*)d_in[11];
  const float* ba2    = (const float*)d_in[12];
  const float* Wv     = (const float*)d_in[13];
  const float* bv     = (const float*)d_in[14];
  const float* Wo     = (const float*)d_in[15];
  const float* bo     = (const float*)d_in[16];
  float* out = (float*)d_out;

  char* ws = (char*)d_ws;
  // layout (total 122,556,416 B):
  unsigned short* v_ws = (unsigned short*)ws;                   // 44,564,480
  float* proj_ws = (float*)(ws + 44564480);                     // 33,554,432
  float* off2_ws = (float*)(ws + 78118912);                     // 16,777,216
  unsigned short* wcat_ws = (unsigned short*)(ws + 78118912);   // aliases off2
  unsigned short* hidb_ws = (unsigned short*)(ws + 94896128);   //  2,097,152
  float* acc_ws  = (float*)(ws + 96993280);                     //  8,388,608
  unsigned short* wtv_ws  = (unsigned short*)(ws + 122159104);  //    131,072
  unsigned short* wto_ws  = (unsigned short*)(ws + 122290176);  //    131,072
  unsigned short* wa2t_ws = (unsigned short*)(ws + 122421248);  //    131,072
  float* bcat_ws = (float*)(ws + 122552320);                    //      4,096

  // 1) all weight preps, one dispatch
  prep_weights<<<1796, 256, 0, stream>>>(Wv, Wo, W_off, W_attn, Wa1, Wa2,
                                         b_off, b_attn, ba1, wtv_ws, wto_ws,
                                         wcat_ws, wa2t_ws, bcat_ws);
  // 2) fused: v = value@Wv+bv (bf16) AND proj/hidb = query@wcat+bcat
  gemm_fused<<<1024, 512, 0, stream>>>(value, wtv_ws, bv, v_ws, query,
                                       wcat_ws, bcat_ws, proj_ws, hidb_ws);
  // 3) off2 = hidb @ Wa2 + ba2
  gemm_mfma<0, 1, 128><<<dim3(NQ_SZ / 128, 2), 512, 0, stream>>>(
      hidb_ws, wa2t_ws, ba2, off2_ws, 512);
  // 4) sampling (softmax+grid fused in)
  sample_kernel<<<NQ_SZ / 2, 256, 0, stream>>>(v_ws, proj_ws, off2_ws, refpts,
                                               acc_ws);
  // 5) out = acc @ Wo + bo
  gemm_mfma<0, 0, 256><<<dim3(NQ_SZ / 128, 1), 512, 0, stream>>>(
      acc_ws, wto_ws, bo, out, 256);
}

// Round 11
// 125.532 us; speedup vs baseline: 1.8849x; 1.1338x over previous
//
#include <hip/hip_runtime.h>
#include <math.h>

#define B_SZ 4
#define LQ_SZ 2048
#define C_SZ 256
#define NH_SZ 8
#define NL_SZ 4
#define NP_SZ 8
#define HD_SZ 32
#define LV_SZ 21760
#define NQ_SZ (B_SZ * LQ_SZ)   // 8192
#define MV_SZ (B_SZ * LV_SZ)   // 87040

typedef __attribute__((ext_vector_type(8))) short bf16x8;
typedef __attribute__((ext_vector_type(8))) unsigned short ushort8;
typedef __attribute__((ext_vector_type(4))) float f32x4;

__device__ __forceinline__ float bf2f(unsigned short u) {
  union { float f; unsigned v; } x;
  x.v = ((unsigned)u) << 16;
  return x.f;
}
__device__ __forceinline__ unsigned short f2bf(float f) {
  union { float f; unsigned v; } x;
  x.f = f;
  unsigned r = x.v + 0x7fffu + ((x.v >> 16) & 1u);
  return (unsigned short)(r >> 16);
}

// 8x f32 -> bf16x8 via v_cvt_pk_bf16_f32 (RNE, same as f2bf)
__device__ __forceinline__ bf16x8 cvt8(f32x4 a, f32x4 b) {
  union { unsigned u[4]; bf16x8 v; } r;
  asm("v_cvt_pk_bf16_f32 %0, %1, %2" : "=v"(r.u[0]) : "v"(a[0]), "v"(a[1]));
  asm("v_cvt_pk_bf16_f32 %0, %1, %2" : "=v"(r.u[1]) : "v"(a[2]), "v"(a[3]));
  asm("v_cvt_pk_bf16_f32 %0, %1, %2" : "=v"(r.u[2]) : "v"(b[0]), "v"(b[1]));
  asm("v_cvt_pk_bf16_f32 %0, %1, %2" : "=v"(r.u[3]) : "v"(b[2]), "v"(b[3]));
  return r.v;
}

// ---------------------------------------------------------------------------
// One-shot weight prep (grid 1796 x 256).
// ---------------------------------------------------------------------------
__global__ void prep_weights(
    const float* __restrict__ Wv, const float* __restrict__ Wo,
    const float* __restrict__ W_off, const float* __restrict__ W_attn,
    const float* __restrict__ Wa1, const float* __restrict__ Wa2,
    const float* __restrict__ b_off, const float* __restrict__ b_attn,
    const float* __restrict__ ba1,
    unsigned short* __restrict__ wtv, unsigned short* __restrict__ wto,
    unsigned short* __restrict__ wcat, unsigned short* __restrict__ wa2t,
    float* __restrict__ bcat) {
  const int bid = blockIdx.x, t = threadIdx.x;
  if (bid < 256) {
    wtv[bid * 256 + t] = f2bf(Wv[t * 256 + bid]);
  } else if (bid < 512) {
    const int n = bid - 256;
    wto[n * 256 + t] = f2bf(Wo[t * 256 + n]);
  } else if (bid < 1536) {
    const int n = bid - 512;
    float v;
    if (n < 512) v = W_off[t * 512 + n];
    else if (n < 768) v = W_attn[t * 256 + (n - 512)];
    else if (n < 896) v = Wa1[t * 128 + (n - 768)];
    else v = 0.f;
    wcat[n * 256 + t] = f2bf(v);
  } else if (bid < 1792) {
    const int idx = (bid - 1536) * 256 + t;     // < 65536
    const int n = idx >> 7, k = idx & 127;
    wa2t[n * 128 + k] = f2bf(Wa2[k * 512 + n]);
  } else {
    const int idx = (bid - 1792) * 256 + t;     // < 1024
    float v;
    if (idx < 512) v = b_off[idx];
    else if (idx < 768) v = b_attn[idx - 512];
    else if (idx < 896) v = ba1[idx - 768];
    else v = 0.f;
    bcat[idx] = v;
  }
}

// ---------------------------------------------------------------------------
// Front-loaded single-barrier MFMA GEMM.
// C[M, n_total] = A[M, K_DIM] @ Wt^T + bias; Wt bf16 [n][K_DIM].
// Block = 512 thr = 8 waves; wave w owns rows bm+w*16 (16) x 128 cols (bn0).
// Sequence: (a) cooperatively stage B-tile (128 x K_DIM bf16) into
// XOR-swizzled LDS, (b) each lane front-loads its ENTIRE A fragment set
// into registers (KSTEPS independent 1-KB wave-loads), (c) ONE barrier,
// (d) pure reg+LDS MFMA loop - zero global accesses, zero barriers.
// Swizzle: 16-B chunk c of B-row r stored at c ^ (r&7); read side XORs the
// same. grid = (n_tiles, M/128); n fast so row-sharing blocks are adjacent.
// MODE: 0 = f32 out, 1 = bf16 out, 2 = proj (col<768 f32; 768..895 relu
// bf16 -> aux).
// ---------------------------------------------------------------------------
template <int MODE, int A_BF16, int K_DIM>
__global__ __launch_bounds__(512, 2) void gemm_wave(
    const void* __restrict__ Ain, const unsigned short* __restrict__ Wt,
    const float* __restrict__ bias, void* __restrict__ Cout,
    unsigned short* __restrict__ aux, int n_total) {
  constexpr int KSTEPS = K_DIM / 32;
  constexpr int CHUNKS = K_DIM / 8;           // 16-B chunks per B row
  __shared__ unsigned short Bs[128 * K_DIM];  // 64 KB (K=256) / 32 KB (K=128)
  const int tid = threadIdx.x;
  const int lane = tid & 63;
  const int w = tid >> 6;
  const int rowc = lane & 15, rowg = lane >> 4;
  const int bn0 = blockIdx.x * 128;
  const long bm = (long)blockIdx.y * 128;

  // ---- (a) B staging: 4 threads per row, CHUNKS/4 chunks each ----
  {
    const int row = tid >> 2, qq = tid & 3;
    const unsigned short* src =
        Wt + (long)(bn0 + row) * K_DIM + qq * (K_DIM / 4);
    char* dstrow = (char*)Bs + row * (K_DIM * 2);
#pragma unroll
    for (int i = 0; i < CHUNKS / 4; ++i) {
      const int cl = qq * (CHUNKS / 4) + i;
      ushort8 u = *(const ushort8*)(src + i * 8);
      *(ushort8*)(dstrow + (cl ^ (row & 7)) * 16) = u;
    }
  }

  // ---- (b) A front-load into fragment registers ----
  bf16x8 afrag[KSTEPS];
  if constexpr (A_BF16) {
    const unsigned short* ap =
        (const unsigned short*)Ain + (bm + w * 16 + rowc) * (long)K_DIM +
        rowg * 8;
#pragma unroll
    for (int ks = 0; ks < KSTEPS; ++ks)
      afrag[ks] = *(const bf16x8*)(ap + ks * 32);
  } else {
    const float* ap =
        (const float*)Ain + (bm + w * 16 + rowc) * (long)K_DIM + rowg * 8;
#pragma unroll
    for (int ks = 0; ks < KSTEPS; ++ks) {
      f32x4 x0 = *(const f32x4*)(ap + ks * 32);
      f32x4 x1 = *(const f32x4*)(ap + ks * 32 + 4);
      afrag[ks] = cvt8(x0, x1);
    }
  }

  f32x4 acc[8];
#pragma unroll
  for (int n = 0; n < 8; ++n) acc[n] = (f32x4){0.f, 0.f, 0.f, 0.f};

  // ---- (c) the only barrier ----
  __syncthreads();

  // ---- (d) MFMA loop: operands from regs + LDS only ----
#pragma unroll
  for (int ks = 0; ks < KSTEPS; ++ks) {
#pragma unroll
    for (int n = 0; n < 8; ++n) {
      const int col = n * 16 + rowc;
      const int cs = (ks * 4 + rowg) ^ (col & 7);
      bf16x8 bf =
          *(const bf16x8*)((const char*)Bs + col * (K_DIM * 2) + cs * 16);
      acc[n] = __builtin_amdgcn_mfma_f32_16x16x32_bf16(afrag[ks], bf, acc[n],
                                                       0, 0, 0);
    }
  }

  // ---- epilogue: C[bm + w*16 + rowg*4 + j][bn0 + n*16 + rowc] ----
#pragma unroll
  for (int n = 0; n < 8; ++n) {
    const int col = bn0 + n * 16 + rowc;
    const float bb = bias[col];
#pragma unroll
    for (int j = 0; j < 4; ++j) {
      const long row = bm + w * 16 + rowg * 4 + j;
      const float val = acc[n][j] + bb;
      if constexpr (MODE == 0) {
        ((float*)Cout)[row * n_total + col] = val;
      } else if constexpr (MODE == 1) {
        ((unsigned short*)Cout)[row * n_total + col] = f2bf(val);
      } else {
        if (col < 768) {
          ((float*)Cout)[row * n_total + col] = val;
        } else if (col < 896) {
          aux[row * 128 + (col - 768)] = f2bf(fmaxf(val, 0.f));
        }
      }
    }
  }
}

// ---------------------------------------------------------------------------
// Sampling with fused finalize (round-10, passing): phase 1 computes softmax
// + grid + corner offsets/weights into LDS; phase 2 gathers v (bf16).
// Block = 2 queries, 256 threads.
// ---------------------------------------------------------------------------
__global__ __launch_bounds__(256) void sample_kernel(
    const unsigned short* __restrict__ v, const float* __restrict__ proj,
    const float* __restrict__ off2, const float* __restrict__ refpts,
    float* __restrict__ acc_out) {
  __shared__ int4 sidx[512];
  __shared__ float4 sw[512];
  const int tid = threadIdx.x;
  const long q0 = (long)blockIdx.x * 2;
  const int b = (int)(q0 >> 11);
  constexpr int starts[4] = {0, 16384, 20480, 21504};

#pragma unroll
  for (int ss = 0; ss < 2; ++ss) {
    const int s = tid + ss * 256;
    const int qq = s >> 8, j = s & 255;       // j = h*32 + l*8 + p
    const long qi = q0 + qq;
    const int l = (j >> 3) & 3;
    const int HW = 128 >> l;
    const float fHW = (float)HW;

    const float logit = proj[qi * 1024 + 512 + j];
    float mx = logit;
#pragma unroll
    for (int mask = 16; mask > 0; mask >>= 1)
      mx = fmaxf(mx, __shfl_xor(mx, mask));
    const float e = __expf(logit - mx);
    float sum = e;
#pragma unroll
    for (int mask = 16; mask > 0; mask >>= 1) sum += __shfl_xor(sum, mask);
    const float wgt = e / sum;

    const float2 po = *(const float2*)(proj + qi * 1024 + 2 * j);
    const float2 o2 = *(const float2*)(off2 + qi * 512 + 2 * j);
    const float2 rp = *(const float2*)(refpts + qi * 8 + l * 2);
    const float rnorm = 1.f / fHW;
    const float gx = (rp.x + (po.x + 0.1f * o2.x) * rnorm) * 2.f - 1.f;
    const float gy = (rp.y + (po.y + 0.1f * o2.y) * rnorm) * 2.f - 1.f;

    const float x = ((gx + 1.f) * fHW - 1.f) * 0.5f;
    const float y = ((gy + 1.f) * fHW - 1.f) * 0.5f;
    const float x0f = floorf(x), y0f = floorf(y);
    const float lx = x - x0f, ly = y - y0f;
    const int ix0 = (int)x0f, iy0 = (int)y0f;
    const int ix1 = ix0 + 1, iy1 = iy0 + 1;
    const float vx0 = (ix0 >= 0 && ix0 < HW) ? 1.f : 0.f;
    const float vx1 = (ix1 >= 0 && ix1 < HW) ? 1.f : 0.f;
    const float vy0 = (iy0 >= 0 && iy0 < HW) ? 1.f : 0.f;
    const float vy1 = (iy1 >= 0 && iy1 < HW) ? 1.f : 0.f;
    const int cx0 = min(max(ix0, 0), HW - 1);
    const int cx1 = min(max(ix1, 0), HW - 1);
    const int cy0 = min(max(iy0, 0), HW - 1);
    const int cy1 = min(max(iy1, 0), HW - 1);
    const int base = starts[l];
    int4 o;  // byte offsets into v (256 ch * 2 B per location)
    o.x = (base + cy0 * HW + cx0) * 512;
    o.y = (base + cy0 * HW + cx1) * 512;
    o.z = (base + cy1 * HW + cx0) * 512;
    o.w = (base + cy1 * HW + cx1) * 512;
    sidx[s] = o;
    float4 wv;
    wv.x = (1.f - lx) * (1.f - ly) * vx0 * vy0 * wgt;
    wv.y = lx * (1.f - ly) * vx1 * vy0 * wgt;
    wv.z = (1.f - lx) * ly * vx0 * vy1 * wgt;
    wv.w = lx * ly * vx1 * vy1 * wgt;
    sw[s] = wv;
  }
  __syncthreads();

  const int qq = tid >> 7, h = (tid >> 4) & 7, dp = tid & 15;
  const char* vb =
      (const char*)v + ((long)b * LV_SZ * 256 + h * 32 + dp * 2) * 2;
  const int sbase = qq * 256 + h * 32;
  float acc0 = 0.f, acc1 = 0.f;
#pragma unroll 8
  for (int j = 0; j < 32; ++j) {
    const int4 o = sidx[sbase + j];
    const float4 w = sw[sbase + j];
    const ushort2 u0 = *(const ushort2*)(vb + o.x);
    const ushort2 u1 = *(const ushort2*)(vb + o.y);
    const ushort2 u2 = *(const ushort2*)(vb + o.z);
    const ushort2 u3 = *(const ushort2*)(vb + o.w);
    acc0 = fmaf(bf2f(u0.x), w.x, acc0);
    acc1 = fmaf(bf2f(u0.y), w.x, acc1);
    acc0 = fmaf(bf2f(u1.x), w.y, acc0);
    acc1 = fmaf(bf2f(u1.y), w.y, acc1);
    acc0 = fmaf(bf2f(u2.x), w.z, acc0);
    acc1 = fmaf(bf2f(u2.y), w.z, acc1);
    acc0 = fmaf(bf2f(u3.x), w.w, acc0);
    acc1 = fmaf(bf2f(u3.y), w.w, acc1);
  }
  float2 res = {acc0, acc1};
  *(float2*)(acc_out + (q0 + qq) * 256 + h * 32 + dp * 2) = res;
}

// ---------------------------------------------------------------------------
extern "C" void kernel_launch(void* const* d_in, const int* in_sizes, int n_in,
                              void* d_out, int out_size, void* d_ws,
                              size_t ws_size, hipStream_t stream) {
  const float* query  = (const float*)d_in[0];
  const float* refpts = (const float*)d_in[1];
  const float* value  = (const float*)d_in[2];
  const float* W_off  = (const float*)d_in[5];
  const float* b_off  = (const float*)d_in[6];
  const float* W_attn = (const float*)d_in[7];
  const float* b_attn = (const float*)d_in[8];
  const float* Wa1    = (const float*)d_in[9];
  const float* ba1    = (const float*)d_in[10];
  const float* Wa2    = (const float*)d_in[11];
  const float* ba2    = (const float*)d_in[12];
  const float* Wv     = (const float*)d_in[13];
  const float* bv     = (const float*)d_in[14];
  const float* Wo     = (const float*)d_in[15];
  const float* bo     = (const float*)d_in[16];
  float* out = (float*)d_out;

  char* ws = (char*)d_ws;
  // layout (total 122,556,416 B):
  unsigned short* v_ws = (unsigned short*)ws;                   // 44,564,480
  float* proj_ws = (float*)(ws + 44564480);                     // 33,554,432
  float* off2_ws = (float*)(ws + 78118912);                     // 16,777,216
  unsigned short* wcat_ws = (unsigned short*)(ws + 78118912);   // aliases off2
  unsigned short* hidb_ws = (unsigned short*)(ws + 94896128);   //  2,097,152
  float* acc_ws  = (float*)(ws + 96993280);                     //  8,388,608
  unsigned short* wtv_ws  = (unsigned short*)(ws + 122159104);  //    131,072
  unsigned short* wto_ws  = (unsigned short*)(ws + 122290176);  //    131,072
  unsigned short* wa2t_ws = (unsigned short*)(ws + 122421248);  //    131,072
  float* bcat_ws = (float*)(ws + 122552320);                    //      4,096

  // 1) all weight preps, one dispatch
  prep_weights<<<1796, 256, 0, stream>>>(Wv, Wo, W_off, W_attn, Wa1, Wa2,
                                         b_off, b_attn, ba1, wtv_ws, wto_ws,
                                         wcat_ws, wa2t_ws, bcat_ws);
  // 2) v = value @ Wv + bv  (bf16 out); grid (n-tiles fast, m slow)
  gemm_wave<1, 0, 256><<<dim3(2, MV_SZ / 128), 512, 0, stream>>>(
      value, wtv_ws, bv, v_ws, nullptr, 256);
  // 3) proj = query @ wcat + bcat (cols<768 f32; 768..895 relu->hidb;
  //    dead tail tile skipped: grid.x = 7)
  gemm_wave<2, 0, 256><<<dim3(7, NQ_SZ / 128), 512, 0, stream>>>(
      query, wcat_ws, bcat_ws, proj_ws, hidb_ws, 1024);
  // 4) off2 = hidb @ Wa2 + ba2
  gemm_wave<0, 1, 128><<<dim3(4, NQ_SZ / 128), 512, 0, stream>>>(
      hidb_ws, wa2t_ws, ba2, off2_ws, nullptr, 512);
  // 5) sampling (softmax+grid fused in)
  sample_kernel<<<NQ_SZ / 2, 256, 0, stream>>>(v_ws, proj_ws, off2_ws, refpts,
                                               acc_ws);
  // 6) out = acc @ Wo + bo
  gemm_wave<0, 0, 256><<<dim3(2, NQ_SZ / 128), 512, 0, stream>>>(
      acc_ws, wto_ws, bo, out, nullptr, 256);
}

// Round 12
// 122.671 us; speedup vs baseline: 1.9288x; 1.0233x over previous
//
#include <hip/hip_runtime.h>
#include <math.h>

#define B_SZ 4
#define LQ_SZ 2048
#define C_SZ 256
#define NH_SZ 8
#define NL_SZ 4
#define NP_SZ 8
#define HD_SZ 32
#define LV_SZ 21760
#define NQ_SZ (B_SZ * LQ_SZ)   // 8192
#define MV_SZ (B_SZ * LV_SZ)   // 87040

typedef __attribute__((ext_vector_type(8))) short bf16x8;
typedef __attribute__((ext_vector_type(8))) unsigned short ushort8;
typedef __attribute__((ext_vector_type(4))) float f32x4;

__device__ __forceinline__ float bf2f(unsigned short u) {
  union { float f; unsigned v; } x;
  x.v = ((unsigned)u) << 16;
  return x.f;
}
__device__ __forceinline__ unsigned short f2bf(float f) {
  union { float f; unsigned v; } x;
  x.f = f;
  unsigned r = x.v + 0x7fffu + ((x.v >> 16) & 1u);
  return (unsigned short)(r >> 16);
}

// 8x f32 -> bf16x8 via v_cvt_pk_bf16_f32 (RNE, same as f2bf)
__device__ __forceinline__ bf16x8 cvt8(f32x4 a, f32x4 b) {
  union { unsigned u[4]; bf16x8 v; } r;
  asm("v_cvt_pk_bf16_f32 %0, %1, %2" : "=v"(r.u[0]) : "v"(a[0]), "v"(a[1]));
  asm("v_cvt_pk_bf16_f32 %0, %1, %2" : "=v"(r.u[1]) : "v"(a[2]), "v"(a[3]));
  asm("v_cvt_pk_bf16_f32 %0, %1, %2" : "=v"(r.u[2]) : "v"(b[0]), "v"(b[1]));
  asm("v_cvt_pk_bf16_f32 %0, %1, %2" : "=v"(r.u[3]) : "v"(b[2]), "v"(b[3]));
  return r.v;
}

// bank-permute: bijective on 0..7, bit2 tracks x&1 (write-side spread),
// distinct over any 8 consecutive x (read-side spread).
__device__ __forceinline__ int swz(int x) {
  return ((x & 1) << 2) | ((x >> 1) & 3);
}

// ---------------------------------------------------------------------------
// One-shot weight prep (grid 1796 x 256).
// ---------------------------------------------------------------------------
__global__ void prep_weights(
    const float* __restrict__ Wv, const float* __restrict__ Wo,
    const float* __restrict__ W_off, const float* __restrict__ W_attn,
    const float* __restrict__ Wa1, const float* __restrict__ Wa2,
    const float* __restrict__ b_off, const float* __restrict__ b_attn,
    const float* __restrict__ ba1,
    unsigned short* __restrict__ wtv, unsigned short* __restrict__ wto,
    unsigned short* __restrict__ wcat, unsigned short* __restrict__ wa2t,
    float* __restrict__ bcat) {
  const int bid = blockIdx.x, t = threadIdx.x;
  if (bid < 256) {
    wtv[bid * 256 + t] = f2bf(Wv[t * 256 + bid]);
  } else if (bid < 512) {
    const int n = bid - 256;
    wto[n * 256 + t] = f2bf(Wo[t * 256 + n]);
  } else if (bid < 1536) {
    const int n = bid - 512;
    float v;
    if (n < 512) v = W_off[t * 512 + n];
    else if (n < 768) v = W_attn[t * 256 + (n - 512)];
    else if (n < 896) v = Wa1[t * 128 + (n - 768)];
    else v = 0.f;
    wcat[n * 256 + t] = f2bf(v);
  } else if (bid < 1792) {
    const int idx = (bid - 1536) * 256 + t;     // < 65536
    const int n = idx >> 7, k = idx & 127;
    wa2t[n * 128 + k] = f2bf(Wa2[k * 512 + n]);
  } else {
    const int idx = (bid - 1792) * 256 + t;     // < 1024
    float v;
    if (idx < 512) v = b_off[idx];
    else if (idx < 768) v = b_attn[idx - 512];
    else if (idx < 896) v = ba1[idx - 768];
    else v = 0.f;
    bcat[idx] = v;
  }
}

// ---------------------------------------------------------------------------
// Front-loaded single-barrier MFMA GEMM, v2.
// C[M, n_total] = A[M, K_DIM] @ Wt^T + bias; Wt bf16 [n][K_DIM].
// Block = 512 thr = 8 waves; wave w owns rows bm+w*16 x 128 cols (bn0).
// (a) stage B tile into LDS, conflict-free: thread qq of a row owns chunks
//     cl = i*4+qq (qq in bank bits); store at chunk cl ^ swz(row).
// (b) lane front-loads its whole A fragment set (KSTEPS indep 1KB loads).
// (c) ONE barrier. (d) pure reg+LDS MFMA loop, OPERANDS SWAPPED:
//     mfma(bfrag, afrag) -> lane holds C[bm+w*16+rowc][col.. +4 consecutive]
//     -> vectorized 8B/16B epilogue stores.
// MODE: 0 = f32 out, 1 = bf16 out, 2 = proj (bn0<768 f32; bn0==768 tile ->
// relu bf16 into aux[.,128]).
// ---------------------------------------------------------------------------
template <int MODE, int A_BF16, int K_DIM>
__global__ __launch_bounds__(512, 2) void gemm_wave(
    const void* __restrict__ Ain, const unsigned short* __restrict__ Wt,
    const float* __restrict__ bias, void* __restrict__ Cout,
    unsigned short* __restrict__ aux, int n_total) {
  constexpr int KSTEPS = K_DIM / 32;
  constexpr int CHUNKS = K_DIM / 8;           // 16-B chunks per B row
  __shared__ unsigned short Bs[128 * K_DIM];  // 64 KB (K=256) / 32 KB (K=128)
  const int tid = threadIdx.x;
  const int lane = tid & 63;
  const int w = tid >> 6;
  const int rowc = lane & 15, rowg = lane >> 4;
  const int bn0 = blockIdx.x * 128;
  const long bm = (long)blockIdx.y * 128;

  // ---- (a) B staging: 4 threads per row, interleaved chunks ----
  {
    const int row = tid >> 2, qq = tid & 3;
    const unsigned short* src = Wt + (long)(bn0 + row) * K_DIM;
    char* dstrow = (char*)Bs + row * (K_DIM * 2);
    const int sz = swz(row);
#pragma unroll
    for (int i = 0; i < CHUNKS / 4; ++i) {
      const int cl = i * 4 + qq;
      ushort8 u = *(const ushort8*)(src + cl * 8);
      *(ushort8*)(dstrow + (cl ^ sz) * 16) = u;
    }
  }

  // ---- (b) A front-load into fragment registers ----
  bf16x8 afrag[KSTEPS];
  if constexpr (A_BF16) {
    const unsigned short* ap =
        (const unsigned short*)Ain + (bm + w * 16 + rowc) * (long)K_DIM +
        rowg * 8;
#pragma unroll
    for (int ks = 0; ks < KSTEPS; ++ks)
      afrag[ks] = *(const bf16x8*)(ap + ks * 32);
  } else {
    const float* ap =
        (const float*)Ain + (bm + w * 16 + rowc) * (long)K_DIM + rowg * 8;
#pragma unroll
    for (int ks = 0; ks < KSTEPS; ++ks) {
      f32x4 x0 = *(const f32x4*)(ap + ks * 32);
      f32x4 x1 = *(const f32x4*)(ap + ks * 32 + 4);
      afrag[ks] = cvt8(x0, x1);
    }
  }

  f32x4 acc[8];
#pragma unroll
  for (int n = 0; n < 8; ++n) acc[n] = (f32x4){0.f, 0.f, 0.f, 0.f};

  // ---- (c) the only barrier ----
  __syncthreads();

  // ---- (d) MFMA loop, swapped operands ----
#pragma unroll
  for (int ks = 0; ks < KSTEPS; ++ks) {
#pragma unroll
    for (int n = 0; n < 8; ++n) {
      const int col = n * 16 + rowc;
      const int cs = (ks * 4 + rowg) ^ swz(col);
      bf16x8 bf =
          *(const bf16x8*)((const char*)Bs + col * (K_DIM * 2) + cs * 16);
      acc[n] = __builtin_amdgcn_mfma_f32_16x16x32_bf16(bf, afrag[ks], acc[n],
                                                       0, 0, 0);
    }
  }

  // ---- epilogue: lane holds C[bm+w*16+rowc][bn0+n*16+rowg*4 + 0..3] ----
  const long row = bm + w * 16 + rowc;
#pragma unroll
  for (int n = 0; n < 8; ++n) {
    const int col = bn0 + n * 16 + rowg * 4;
    const float4 bb = *(const float4*)(bias + col);
    const float v0 = acc[n][0] + bb.x;
    const float v1 = acc[n][1] + bb.y;
    const float v2 = acc[n][2] + bb.z;
    const float v3 = acc[n][3] + bb.w;
    if constexpr (MODE == 0) {
      float4 s = {v0, v1, v2, v3};
      *(float4*)((float*)Cout + row * n_total + col) = s;
    } else if constexpr (MODE == 1) {
      union { unsigned u[2]; uint2 d; } pk;
      asm("v_cvt_pk_bf16_f32 %0, %1, %2" : "=v"(pk.u[0]) : "v"(v0), "v"(v1));
      asm("v_cvt_pk_bf16_f32 %0, %1, %2" : "=v"(pk.u[1]) : "v"(v2), "v"(v3));
      *(uint2*)((unsigned short*)Cout + row * n_total + col) = pk.d;
    } else {
      if (bn0 < 768) {
        float4 s = {v0, v1, v2, v3};
        *(float4*)((float*)Cout + row * n_total + col) = s;
      } else {
        union { unsigned u[2]; uint2 d; } pk;
        const float r0 = fmaxf(v0, 0.f), r1 = fmaxf(v1, 0.f);
        const float r2 = fmaxf(v2, 0.f), r3 = fmaxf(v3, 0.f);
        asm("v_cvt_pk_bf16_f32 %0, %1, %2" : "=v"(pk.u[0]) : "v"(r0), "v"(r1));
        asm("v_cvt_pk_bf16_f32 %0, %1, %2" : "=v"(pk.u[1]) : "v"(r2), "v"(r3));
        *(uint2*)(aux + row * 128 + (col - 768)) = pk.d;
      }
    }
  }
}

// ---------------------------------------------------------------------------
// Sampling with fused finalize: phase 1 computes softmax + grid + corner
// offsets/weights into LDS; phase 2 gathers v (bf16).
// Block = 2 queries, 256 threads.
// ---------------------------------------------------------------------------
__global__ __launch_bounds__(256) void sample_kernel(
    const unsigned short* __restrict__ v, const float* __restrict__ proj,
    const float* __restrict__ off2, const float* __restrict__ refpts,
    float* __restrict__ acc_out) {
  __shared__ int4 sidx[512];
  __shared__ float4 sw[512];
  const int tid = threadIdx.x;
  const long q0 = (long)blockIdx.x * 2;
  const int b = (int)(q0 >> 11);
  constexpr int starts[4] = {0, 16384, 20480, 21504};

#pragma unroll
  for (int ss = 0; ss < 2; ++ss) {
    const int s = tid + ss * 256;
    const int qq = s >> 8, j = s & 255;       // j = h*32 + l*8 + p
    const long qi = q0 + qq;
    const int l = (j >> 3) & 3;
    const int HW = 128 >> l;
    const float fHW = (float)HW;

    const float logit = proj[qi * 1024 + 512 + j];
    float mx = logit;
#pragma unroll
    for (int mask = 16; mask > 0; mask >>= 1)
      mx = fmaxf(mx, __shfl_xor(mx, mask));
    const float e = __expf(logit - mx);
    float sum = e;
#pragma unroll
    for (int mask = 16; mask > 0; mask >>= 1) sum += __shfl_xor(sum, mask);
    const float wgt = e / sum;

    const float2 po = *(const float2*)(proj + qi * 1024 + 2 * j);
    const float2 o2 = *(const float2*)(off2 + qi * 512 + 2 * j);
    const float2 rp = *(const float2*)(refpts + qi * 8 + l * 2);
    const float rnorm = 1.f / fHW;
    const float gx = (rp.x + (po.x + 0.1f * o2.x) * rnorm) * 2.f - 1.f;
    const float gy = (rp.y + (po.y + 0.1f * o2.y) * rnorm) * 2.f - 1.f;

    const float x = ((gx + 1.f) * fHW - 1.f) * 0.5f;
    const float y = ((gy + 1.f) * fHW - 1.f) * 0.5f;
    const float x0f = floorf(x), y0f = floorf(y);
    const float lx = x - x0f, ly = y - y0f;
    const int ix0 = (int)x0f, iy0 = (int)y0f;
    const int ix1 = ix0 + 1, iy1 = iy0 + 1;
    const float vx0 = (ix0 >= 0 && ix0 < HW) ? 1.f : 0.f;
    const float vx1 = (ix1 >= 0 && ix1 < HW) ? 1.f : 0.f;
    const float vy0 = (iy0 >= 0 && iy0 < HW) ? 1.f : 0.f;
    const float vy1 = (iy1 >= 0 && iy1 < HW) ? 1.f : 0.f;
    const int cx0 = min(max(ix0, 0), HW - 1);
    const int cx1 = min(max(ix1, 0), HW - 1);
    const int cy0 = min(max(iy0, 0), HW - 1);
    const int cy1 = min(max(iy1, 0), HW - 1);
    const int base = starts[l];
    int4 o;  // byte offsets into v (256 ch * 2 B per location)
    o.x = (base + cy0 * HW + cx0) * 512;
    o.y = (base + cy0 * HW + cx1) * 512;
    o.z = (base + cy1 * HW + cx0) * 512;
    o.w = (base + cy1 * HW + cx1) * 512;
    sidx[s] = o;
    float4 wv;
    wv.x = (1.f - lx) * (1.f - ly) * vx0 * vy0 * wgt;
    wv.y = lx * (1.f - ly) * vx1 * vy0 * wgt;
    wv.z = (1.f - lx) * ly * vx0 * vy1 * wgt;
    wv.w = lx * ly * vx1 * vy1 * wgt;
    sw[s] = wv;
  }
  __syncthreads();

  const int qq = tid >> 7, h = (tid >> 4) & 7, dp = tid & 15;
  const char* vb =
      (const char*)v + ((long)b * LV_SZ * 256 + h * 32 + dp * 2) * 2;
  const int sbase = qq * 256 + h * 32;
  float acc0 = 0.f, acc1 = 0.f;
#pragma unroll 8
  for (int j = 0; j < 32; ++j) {
    const int4 o = sidx[sbase + j];
    const float4 w = sw[sbase + j];
    const ushort2 u0 = *(const ushort2*)(vb + o.x);
    const ushort2 u1 = *(const ushort2*)(vb + o.y);
    const ushort2 u2 = *(const ushort2*)(vb + o.z);
    const ushort2 u3 = *(const ushort2*)(vb + o.w);
    acc0 = fmaf(bf2f(u0.x), w.x, acc0);
    acc1 = fmaf(bf2f(u0.y), w.x, acc1);
    acc0 = fmaf(bf2f(u1.x), w.y, acc0);
    acc1 = fmaf(bf2f(u1.y), w.y, acc1);
    acc0 = fmaf(bf2f(u2.x), w.z, acc0);
    acc1 = fmaf(bf2f(u2.y), w.z, acc1);
    acc0 = fmaf(bf2f(u3.x), w.w, acc0);
    acc1 = fmaf(bf2f(u3.y), w.w, acc1);
  }
  float2 res = {acc0, acc1};
  *(float2*)(acc_out + (q0 + qq) * 256 + h * 32 + dp * 2) = res;
}

// ---------------------------------------------------------------------------
extern "C" void kernel_launch(void* const* d_in, const int* in_sizes, int n_in,
                              void* d_out, int out_size, void* d_ws,
                              size_t ws_size, hipStream_t stream) {
  const float* query  = (const float*)d_in[0];
  const float* refpts = (const float*)d_in[1];
  const float* value  = (const float*)d_in[2];
  const float* W_off  = (const float*)d_in[5];
  const float* b_off  = (const float*)d_in[6];
  const float* W_attn = (const float*)d_in[7];
  const float* b_attn = (const float*)d_in[8];
  const float* Wa1    = (const float*)d_in[9];
  const float* ba1    = (const float*)d_in[10];
  const float* Wa2    = (const float*)d_in[11];
  const float* ba2    = (const float*)d_in[12];
  const float* Wv     = (const float*)d_in[13];
  const float* bv     = (const float*)d_in[14];
  const float* Wo     = (const float*)d_in[15];
  const float* bo     = (const float*)d_in[16];
  float* out = (float*)d_out;

  char* ws = (char*)d_ws;
  // layout (total 122,556,416 B):
  unsigned short* v_ws = (unsigned short*)ws;                   // 44,564,480
  float* proj_ws = (float*)(ws + 44564480);                     // 33,554,432
  float* off2_ws = (float*)(ws + 78118912);                     // 16,777,216
  unsigned short* wcat_ws = (unsigned short*)(ws + 78118912);   // aliases off2
  unsigned short* hidb_ws = (unsigned short*)(ws + 94896128);   //  2,097,152
  float* acc_ws  = (float*)(ws + 96993280);                     //  8,388,608
  unsigned short* wtv_ws  = (unsigned short*)(ws + 122159104);  //    131,072
  unsigned short* wto_ws  = (unsigned short*)(ws + 122290176);  //    131,072
  unsigned short* wa2t_ws = (unsigned short*)(ws + 122421248);  //    131,072
  float* bcat_ws = (float*)(ws + 122552320);                    //      4,096

  // 1) all weight preps, one dispatch
  prep_weights<<<1796, 256, 0, stream>>>(Wv, Wo, W_off, W_attn, Wa1, Wa2,
                                         b_off, b_attn, ba1, wtv_ws, wto_ws,
                                         wcat_ws, wa2t_ws, bcat_ws);
  // 2) v = value @ Wv + bv  (bf16 out); grid (n-tiles fast, m slow)
  gemm_wave<1, 0, 256><<<dim3(2, MV_SZ / 128), 512, 0, stream>>>(
      value, wtv_ws, bv, v_ws, nullptr, 256);
  // 3) proj = query @ wcat + bcat (bn0<768 f32; bn0==768 tile relu->hidb)
  gemm_wave<2, 0, 256><<<dim3(7, NQ_SZ / 128), 512, 0, stream>>>(
      query, wcat_ws, bcat_ws, proj_ws, hidb_ws, 1024);
  // 4) off2 = hidb @ Wa2 + ba2
  gemm_wave<0, 1, 128><<<dim3(4, NQ_SZ / 128), 512, 0, stream>>>(
      hidb_ws, wa2t_ws, ba2, off2_ws, nullptr, 512);
  // 5) sampling (softmax+grid fused in)
  sample_kernel<<<NQ_SZ / 2, 256, 0, stream>>>(v_ws, proj_ws, off2_ws, refpts,
                                               acc_ws);
  // 6) out = acc @ Wo + bo
  gemm_wave<0, 0, 256><<<dim3(2, NQ_SZ / 128), 512, 0, stream>>>(
      acc_ws, wto_ws, bo, out, nullptr, 256);
}